// Round 3
// baseline (2967.929 us; speedup 1.0000x reference)
//
#include <hip/hip_runtime.h>
#include <hip/hip_bf16.h>

typedef __hip_bfloat16 bf16;

#define B_    64
#define CH_   512
#define TD_   256
#define H_    4
#define DH_   64
#define TLAT  1000
#define TTXT  512
#define SCALE_ 0.0625f

__device__ __forceinline__ float cvt(float x) { return x; }
__device__ __forceinline__ float cvt(bf16 x)  { return __bfloat162float(x); }
__device__ __forceinline__ void stv(float* p, float v) { *p = v; }
__device__ __forceinline__ void stv(bf16* p, float v)  { *p = __float2bfloat16(v); }

// ---------------------------------------------------------------------------
// dtype probe: increments = arange(1000). fp32 words 1..3 == 1,2,3 iff fp32.
// ---------------------------------------------------------------------------
__global__ void detect_k(const void* inc, int* flag) {
  const float* f = (const float*)inc;
  float err = fabsf(f[1] - 1.f) + fabsf(f[2] - 2.f) + fabsf(f[3] - 3.f);
  *flag = (err < 0.5f) ? 0 : 1;   // 0 = fp32, 1 = bf16
}

// ---------------------------------------------------------------------------
// GEMM for Q/K/V projections:  C[b,m,n] = sum_k A[b,k,m] * W[n,k] + bias[n]
// A (K,M) k-major per batch (external dtype T), C fp32 (M,256) per batch.
// ---------------------------------------------------------------------------
template<typename T>
__device__ __forceinline__ void gemm_qkv_body(
    float (*As)[64], float (*Ws)[68],
    const void* A0v, size_t aoff, const void* Wv, const void* biasv,
    float* C0, int M, int K) {
  const T* A0   = (const T*)A0v + aoff;
  const T* W    = (const T*)Wv;
  const T* bias = (const T*)biasv;
  const int b = blockIdx.z;
  const T* A = A0 + (size_t)b * K * M;
  float* C = C0 + (size_t)b * M * TD_;
  const int m0 = blockIdx.x * 64, n0 = blockIdx.y * 64;
  float acc[4][4] = {};
  const int tid = threadIdx.x;
  const int tm = (tid & 15) * 4, tn = (tid >> 4) * 4;
  for (int k0 = 0; k0 < K; k0 += 32) {
#pragma unroll
    for (int i = 0; i < 8; i++) {          // A tile: coalesced along m
      int idx = i * 256 + tid;
      int kk = idx >> 6, mm = idx & 63;
      int m = m0 + mm;
      As[kk][mm] = (m < M) ? cvt(A[(size_t)(k0 + kk) * M + m]) : 0.f;
    }
#pragma unroll
    for (int i = 0; i < 8; i++) {          // W tile: coalesced along k
      int idx = i * 256 + tid;
      int nn = idx >> 5, kk = idx & 31;
      Ws[kk][nn] = cvt(W[(size_t)(n0 + nn) * K + (k0 + kk)]);
    }
    __syncthreads();
#pragma unroll
    for (int kk = 0; kk < 32; kk++) {
      float4 av = *(const float4*)&As[kk][tm];
      float4 wv4 = *(const float4*)&Ws[kk][tn];
      float a[4] = {av.x, av.y, av.z, av.w};
      float w[4] = {wv4.x, wv4.y, wv4.z, wv4.w};
#pragma unroll
      for (int i = 0; i < 4; i++)
#pragma unroll
        for (int j = 0; j < 4; j++)
          acc[i][j] = fmaf(a[i], w[j], acc[i][j]);
    }
    __syncthreads();
  }
#pragma unroll
  for (int j = 0; j < 4; j++) {
    float bj = cvt(bias[n0 + tn + j]);
#pragma unroll
    for (int i = 0; i < 4; i++) {
      int m = m0 + tm + i;
      if (m < M) C[(size_t)m * TD_ + n0 + tn + j] = acc[i][j] + bj;
    }
  }
}

__global__ __launch_bounds__(256) void gemm_qkv(
    const int* __restrict__ flag, const void* A0, size_t aoff,
    const void* W, const void* bias, float* C0, int M, int K) {
  __shared__ __align__(16) float As[32][64];
  __shared__ __align__(16) float Ws[32][68];
  if (*flag) gemm_qkv_body<bf16>(As, Ws, A0, aoff, W, bias, C0, M, K);
  else       gemm_qkv_body<float>(As, Ws, A0, aoff, W, bias, C0, M, K);
}

// ---------------------------------------------------------------------------
// In-place RoPE on fp32 (Bc, T, 256) buffer. d=h*64+j pairs with h*64+32+j.
// ---------------------------------------------------------------------------
template<typename T>
__device__ __forceinline__ void rope_body(
    float* buf, const void* incv, const void* thetav, int T_, float inv_seq, int total) {
  const T* inc = (const T*)incv;
  const T* theta = (const T*)thetav;
  int gid = blockIdx.x * 256 + threadIdx.x;
  if (gid >= total) return;
  int j = gid & 31;
  int h = (gid >> 5) & 3;
  int t = (gid >> 7) % T_;
  int b = gid / (T_ * 128);
  float ang = cvt(inc[t]) * inv_seq * cvt(theta[j]);
  float s, c;
  __sincosf(ang, &s, &c);
  size_t base = (size_t)(b * T_ + t) * TD_ + h * 64 + j;
  float x1 = buf[base], x2 = buf[base + 32];
  buf[base]      = x1 * c - x2 * s;
  buf[base + 32] = x1 * s + x2 * c;
}

__global__ __launch_bounds__(256) void rope_k(
    const int* __restrict__ flag, float* buf, const void* inc,
    const void* theta, int T_, float inv_seq, int total) {
  if (*flag) rope_body<bf16>(buf, inc, theta, T_, inv_seq, total);
  else       rope_body<float>(buf, inc, theta, T_, inv_seq, total);
}

// ---------------------------------------------------------------------------
// Flash-style attention per (b, h, 64 q rows). All fp32 internal buffers.
// ---------------------------------------------------------------------------
__global__ __launch_bounds__(256) void attn_k(
    const float* __restrict__ Q, const float* __restrict__ Kb,
    const float* __restrict__ Vb, const int* __restrict__ tmask,
    float* __restrict__ AO) {
  const int b = blockIdx.z, h = blockIdx.y, q0 = blockIdx.x * 64;
  __shared__ float qsT[64][65];   // [dh][row]
  __shared__ float ksT[64][33];   // [dh][j]
  __shared__ float vs[32][65];    // [j][dh]
  __shared__ float S[64][33];     // [row][j], reused as P
  __shared__ float red[64][4];
  __shared__ float mrow[64], arow[64], lrow[64];
  __shared__ float maskS[32];
  const int tid = threadIdx.x;
#pragma unroll
  for (int i = 0; i < 16; i++) {           // Q tile, transposed into LDS
    int idx = i * 256 + tid;
    int r = idx >> 6, dh = idx & 63;
    int t = q0 + r;
    qsT[dh][r] = (t < TLAT) ? Q[(size_t)(b * TLAT + t) * TD_ + h * 64 + dh] : 0.f;
  }
  if (tid < 64) { mrow[tid] = -1e30f; lrow[tid] = 0.f; }
  float O[4][4] = {};
  const int tm = (tid & 15) * 4;      // q-row group (4 rows)
  const int tj = (tid >> 4) * 2;      // j group for S compute (2 cols)
  const int td = (tid >> 4) * 4;      // dh group for PV (4 cols)
  const int r = tid & 63, part = tid >> 6;
  __syncthreads();
  for (int kt = 0; kt < TTXT; kt += 32) {
#pragma unroll
    for (int i = 0; i < 8; i++) {          // K (transposed) + V tiles
      int idx = i * 256 + tid;
      int jj = idx >> 6, dh = idx & 63;
      size_t g = (size_t)(b * TTXT + kt + jj) * TD_ + h * 64 + dh;
      ksT[dh][jj] = Kb[g];
      vs[jj][dh]  = Vb[g];
    }
    if (tid < 32) maskS[tid] = (float)tmask[b * TTXT + kt + tid];
    __syncthreads();                       // [A]
    {
      float acc[4][2] = {};
#pragma unroll
      for (int d = 0; d < 64; d++) {
        float a0 = qsT[d][tm], a1 = qsT[d][tm + 1], a2 = qsT[d][tm + 2], a3 = qsT[d][tm + 3];
        float w0 = ksT[d][tj], w1 = ksT[d][tj + 1];
        acc[0][0] = fmaf(a0, w0, acc[0][0]); acc[0][1] = fmaf(a0, w1, acc[0][1]);
        acc[1][0] = fmaf(a1, w0, acc[1][0]); acc[1][1] = fmaf(a1, w1, acc[1][1]);
        acc[2][0] = fmaf(a2, w0, acc[2][0]); acc[2][1] = fmaf(a2, w1, acc[2][1]);
        acc[3][0] = fmaf(a3, w0, acc[3][0]); acc[3][1] = fmaf(a3, w1, acc[3][1]);
      }
#pragma unroll
      for (int i = 0; i < 4; i++)
#pragma unroll
        for (int j = 0; j < 2; j++)
          S[tm + i][tj + j] = (maskS[tj + j] != 0.f) ? acc[i][j] * SCALE_ : -1e30f;
    }
    __syncthreads();                       // [B]
    float pm = -1e30f;
#pragma unroll
    for (int jj = part * 8; jj < part * 8 + 8; jj++) pm = fmaxf(pm, S[r][jj]);
    red[r][part] = pm;
    __syncthreads();                       // [C]
    if (tid < 64) {
      float mo = mrow[tid];
      float mn = fmaxf(fmaxf(red[tid][0], red[tid][1]), fmaxf(red[tid][2], red[tid][3]));
      mn = fmaxf(mn, mo);
      mrow[tid] = mn;
      arow[tid] = __expf(mo - mn);
    }
    __syncthreads();                       // [D]
    {
      float mr = mrow[r];
      float ps = 0.f;
#pragma unroll
      for (int jj = part * 8; jj < part * 8 + 8; jj++) {
        float sv = S[r][jj];
        float p = (sv > -1e29f) ? __expf(sv - mr) : 0.f;
        S[r][jj] = p;
        ps += p;
      }
      red[r][part] = ps;
    }
    __syncthreads();                       // [E]
    if (tid < 64)
      lrow[tid] = arow[tid] * lrow[tid] + red[tid][0] + red[tid][1] + red[tid][2] + red[tid][3];
    float al[4];
#pragma unroll
    for (int i = 0; i < 4; i++) al[i] = arow[tm + i];
#pragma unroll
    for (int i = 0; i < 4; i++)
#pragma unroll
      for (int j = 0; j < 4; j++) O[i][j] *= al[i];
#pragma unroll
    for (int jj = 0; jj < 32; jj++) {      // O += P @ V
      float w0 = vs[jj][td], w1 = vs[jj][td + 1], w2 = vs[jj][td + 2], w3 = vs[jj][td + 3];
      float p0 = S[tm][jj], p1 = S[tm + 1][jj], p2 = S[tm + 2][jj], p3 = S[tm + 3][jj];
      O[0][0] = fmaf(p0, w0, O[0][0]); O[0][1] = fmaf(p0, w1, O[0][1]);
      O[0][2] = fmaf(p0, w2, O[0][2]); O[0][3] = fmaf(p0, w3, O[0][3]);
      O[1][0] = fmaf(p1, w0, O[1][0]); O[1][1] = fmaf(p1, w1, O[1][1]);
      O[1][2] = fmaf(p1, w2, O[1][2]); O[1][3] = fmaf(p1, w3, O[1][3]);
      O[2][0] = fmaf(p2, w0, O[2][0]); O[2][1] = fmaf(p2, w1, O[2][1]);
      O[2][2] = fmaf(p2, w2, O[2][2]); O[2][3] = fmaf(p2, w3, O[2][3]);
      O[3][0] = fmaf(p3, w0, O[3][0]); O[3][1] = fmaf(p3, w1, O[3][1]);
      O[3][2] = fmaf(p3, w2, O[3][2]); O[3][3] = fmaf(p3, w3, O[3][3]);
    }
    __syncthreads();                       // [F]
  }
  float linv[4];
#pragma unroll
  for (int i = 0; i < 4; i++) linv[i] = 1.0f / fmaxf(lrow[tm + i], 1e-20f);
#pragma unroll
  for (int i = 0; i < 4; i++) {
    int t = q0 + tm + i;
    if (t < TLAT) {
#pragma unroll
      for (int j = 0; j < 4; j++)
        AO[(size_t)(b * TLAT + t) * TD_ + h * 64 + td + j] = O[i][j] * linv[i];
    }
  }
}

// ---------------------------------------------------------------------------
// Output projection + residual + mask:
//   Out[b,c,t] = (x[b,c,t] + sum_d AO[b,t,d]*Wo[c,d] + bo[c]) * lmask[b,t]
// ---------------------------------------------------------------------------
template<typename T>
__device__ __forceinline__ void gemm_out_body(
    float (*As)[65], float (*Ws)[65],
    const float* AO, const void* Wv, const void* biasv,
    const void* Xv, size_t xoff, const void* lmv, size_t lmoff,
    void* Outv, size_t ooff) {
  const T* W    = (const T*)Wv;
  const T* bias = (const T*)biasv;
  const T* X    = (const T*)Xv + xoff;
  const T* lm   = (const T*)lmv + lmoff;
  T* Out        = (T*)Outv + ooff;
  const int b = blockIdx.z;
  const int m0 = blockIdx.x * 64;   // t tile
  const int n0 = blockIdx.y * 64;   // c tile
  const float* A = AO + (size_t)b * TLAT * TD_;
  float acc[4][4] = {};
  const int tid = threadIdx.x;
  const int tm = (tid & 15) * 4, tn = (tid >> 4) * 4;
  for (int k0 = 0; k0 < TD_; k0 += 32) {
#pragma unroll
    for (int i = 0; i < 8; i++) {
      int idx = i * 256 + tid;
      int mm = idx >> 5, kk = idx & 31;
      int t = m0 + mm;
      As[kk][mm] = (t < TLAT) ? A[(size_t)t * TD_ + k0 + kk] : 0.f;
    }
#pragma unroll
    for (int i = 0; i < 8; i++) {
      int idx = i * 256 + tid;
      int nn = idx >> 5, kk = idx & 31;
      Ws[kk][nn] = cvt(W[(size_t)(n0 + nn) * TD_ + k0 + kk]);
    }
    __syncthreads();
#pragma unroll
    for (int kk = 0; kk < 32; kk++) {
      float a[4], w[4];
#pragma unroll
      for (int i = 0; i < 4; i++) a[i] = As[kk][tm + i];
#pragma unroll
      for (int j = 0; j < 4; j++) w[j] = Ws[kk][tn + j];
#pragma unroll
      for (int i = 0; i < 4; i++)
#pragma unroll
        for (int j = 0; j < 4; j++)
          acc[i][j] = fmaf(a[i], w[j], acc[i][j]);
    }
    __syncthreads();
  }
#pragma unroll
  for (int j = 0; j < 4; j++) {
    int c = n0 + tn + j;
    float bj = cvt(bias[c]);
#pragma unroll
    for (int i = 0; i < 4; i++) {
      int t = m0 + tm + i;
      if (t < TLAT) {
        size_t gi = (size_t)b * CH_ * TLAT + (size_t)c * TLAT + t;
        float val = acc[i][j] + bj + cvt(X[gi]);
        val *= cvt(lm[b * TLAT + t]);
        stv(&Out[gi], val);
      }
    }
  }
}

__global__ __launch_bounds__(256) void gemm_out(
    const int* __restrict__ flag, const float* AO, const void* W,
    const void* bias, const void* X, size_t xoff,
    const void* lmask, size_t lmoff, void* Out, size_t ooff) {
  __shared__ float As[32][65];
  __shared__ float Ws[32][65];
  if (*flag) gemm_out_body<bf16>(As, Ws, AO, W, bias, X, xoff, lmask, lmoff, Out, ooff);
  else       gemm_out_body<float>(As, Ws, AO, W, bias, X, xoff, lmask, lmoff, Out, ooff);
}

extern "C" void kernel_launch(void* const* d_in, const int* in_sizes, int n_in,
                              void* d_out, int out_size, void* d_ws, size_t ws_size,
                              hipStream_t stream) {
  const void* x        = d_in[0];
  const void* text_emb = d_in[1];
  const void* lmask    = d_in[2];
  const int*  tmask    = (const int*)d_in[3];
  const void* Wq = d_in[4];
  const void* bq = d_in[5];
  const void* Wk = d_in[6];
  const void* bk = d_in[7];
  const void* Wv = d_in[8];
  const void* bv = d_in[9];
  const void* Wo = d_in[10];
  const void* bo = d_in[11];
  const void* theta = d_in[12];
  const void* inc   = d_in[13];

  int* dflag = (int*)d_ws;
  float* scratch = (float*)((char*)d_ws + 256);
  size_t avail = (ws_size > 256) ? ws_size - 256 : 0;

  // Per-batch fp32 scratch: q(1000*256) + k(512*256) + v(512*256) + ao(1000*256)
  const size_t per_b_elems = (size_t)TD_ * (TLAT + TTXT + TTXT + TLAT); // 774144
  const size_t per_b_bytes = per_b_elems * sizeof(float);               // ~3.1 MB
  int Bc = (int)(avail / per_b_bytes);
  if (Bc > B_) Bc = B_;
  if (Bc < 1) Bc = 1;

  float* qbuf  = scratch;
  float* kbuf  = qbuf + (size_t)Bc * TLAT * TD_;
  float* vbuf  = kbuf + (size_t)Bc * TTXT * TD_;
  float* aobuf = vbuf + (size_t)Bc * TTXT * TD_;

  detect_k<<<1, 1, 0, stream>>>(inc, dflag);

  for (int b0 = 0; b0 < B_; b0 += Bc) {
    int bn = B_ - b0; if (bn > Bc) bn = Bc;
    size_t xoff   = (size_t)b0 * CH_ * TLAT;
    size_t emboff = (size_t)b0 * TD_ * TTXT;

    gemm_qkv<<<dim3(16, 4, bn), 256, 0, stream>>>(dflag, x,        xoff,   Wq, bq, qbuf, TLAT, CH_);
    gemm_qkv<<<dim3(8,  4, bn), 256, 0, stream>>>(dflag, text_emb, emboff, Wk, bk, kbuf, TTXT, TD_);
    gemm_qkv<<<dim3(8,  4, bn), 256, 0, stream>>>(dflag, text_emb, emboff, Wv, bv, vbuf, TTXT, TD_);

    int totq = bn * TLAT * 128;
    rope_k<<<(totq + 255) / 256, 256, 0, stream>>>(dflag, qbuf, inc, theta, TLAT, 1.0f / TLAT, totq);
    int totk = bn * TTXT * 128;
    rope_k<<<(totk + 255) / 256, 256, 0, stream>>>(dflag, kbuf, inc, theta, TTXT, 1.0f / TTXT, totk);

    attn_k<<<dim3(16, H_, bn), 256, 0, stream>>>(qbuf, kbuf, vbuf, tmask + (size_t)b0 * TTXT, aobuf);

    gemm_out<<<dim3(16, 8, bn), 256, 0, stream>>>(dflag, aobuf, Wo, bo,
                                                  x, xoff, lmask, (size_t)b0 * TLAT,
                                                  d_out, xoff);
  }
}

// Round 4
// 1415.014 us; speedup vs baseline: 2.0975x; 2.0975x over previous
//
#include <hip/hip_runtime.h>
#include <hip/hip_bf16.h>

typedef __hip_bfloat16 bf16;
typedef __attribute__((ext_vector_type(8))) short short8;
typedef __attribute__((ext_vector_type(4))) float float4v;

#define B_    64
#define CH_   512
#define TD_   256
#define H_    4
#define DH_   64
#define TLAT  1000
#define TTXT  512
#define SCALE_ 0.0625f

__device__ __forceinline__ float cvt(float x) { return x; }
__device__ __forceinline__ float cvt(bf16 x)  { return __bfloat162float(x); }
__device__ __forceinline__ void stv(float* p, float v) { *p = v; }
__device__ __forceinline__ void stv(bf16* p, float v)  { *p = __float2bfloat16(v); }

__device__ __forceinline__ unsigned short f2bu(float f) {
  bf16 h = __float2bfloat16(f);
  unsigned short u; __builtin_memcpy(&u, &h, 2); return u;
}
__device__ __forceinline__ float bu2f(unsigned short u) {
  bf16 h; __builtin_memcpy(&h, &u, 2); return __bfloat162float(h);
}

// ---------------------------------------------------------------------------
// dtype probe: increments = arange(1000). fp32 words 1..3 == 1,2,3 iff fp32.
// ---------------------------------------------------------------------------
__global__ void detect_k(const void* inc, int* flag) {
  const float* f = (const float*)inc;
  float err = fabsf(f[1] - 1.f) + fabsf(f[2] - 2.f) + fabsf(f[3] - 3.f);
  *flag = (err < 0.5f) ? 0 : 1;   // 0 = fp32, 1 = bf16
}

// ---------------------------------------------------------------------------
// Projection GEMM:  C[b,m,n] = sum_k A[b,k,m] * W[n,k] + bias[n]
// Output bf16 (ushort bits). trans==0: C[(b*M+m)*256+n]; trans==1 (for V):
// C^T[(b*256+n)*M+m]  (key-contiguous rows for the attention b-frag).
// ---------------------------------------------------------------------------
template<typename T>
__device__ __forceinline__ void gemm_proj_body(
    float (*As)[64], float (*Ws)[68],
    const void* A0v, size_t aoff, const void* Wv, const void* biasv,
    unsigned short* C0, int M, int K, int trans) {
  const T* A0   = (const T*)A0v + aoff;
  const T* W    = (const T*)Wv;
  const T* bias = (const T*)biasv;
  const int b = blockIdx.z;
  const T* A = A0 + (size_t)b * K * M;
  const int m0 = blockIdx.x * 64, n0 = blockIdx.y * 64;
  float acc[4][4] = {};
  const int tid = threadIdx.x;
  const int tm = (tid & 15) * 4, tn = (tid >> 4) * 4;
  for (int k0 = 0; k0 < K; k0 += 32) {
#pragma unroll
    for (int i = 0; i < 8; i++) {          // A tile: coalesced along m
      int idx = i * 256 + tid;
      int kk = idx >> 6, mm = idx & 63;
      int m = m0 + mm;
      As[kk][mm] = (m < M) ? cvt(A[(size_t)(k0 + kk) * M + m]) : 0.f;
    }
#pragma unroll
    for (int i = 0; i < 8; i++) {          // W tile: coalesced along k
      int idx = i * 256 + tid;
      int nn = idx >> 5, kk = idx & 31;
      Ws[kk][nn] = cvt(W[(size_t)(n0 + nn) * K + (k0 + kk)]);
    }
    __syncthreads();
#pragma unroll
    for (int kk = 0; kk < 32; kk++) {
      float4 av = *(const float4*)&As[kk][tm];
      float4 wv4 = *(const float4*)&Ws[kk][tn];
      float a[4] = {av.x, av.y, av.z, av.w};
      float w[4] = {wv4.x, wv4.y, wv4.z, wv4.w};
#pragma unroll
      for (int i = 0; i < 4; i++)
#pragma unroll
        for (int j = 0; j < 4; j++)
          acc[i][j] = fmaf(a[i], w[j], acc[i][j]);
    }
    __syncthreads();
  }
  if (trans == 0) {
    unsigned short* C = C0 + (size_t)b * M * TD_;
#pragma unroll
    for (int j = 0; j < 4; j++) {
      float bj = cvt(bias[n0 + tn + j]);
#pragma unroll
      for (int i = 0; i < 4; i++) {
        int m = m0 + tm + i;
        if (m < M) C[(size_t)m * TD_ + n0 + tn + j] = f2bu(acc[i][j] + bj);
      }
    }
  } else {
    unsigned short* C = C0 + (size_t)b * TD_ * M;
#pragma unroll
    for (int j = 0; j < 4; j++) {
      int n = n0 + tn + j;
      float bj = cvt(bias[n]);
#pragma unroll
      for (int i = 0; i < 4; i++) {
        int m = m0 + tm + i;
        if (m < M) C[(size_t)n * M + m] = f2bu(acc[i][j] + bj);
      }
    }
  }
}

__global__ __launch_bounds__(256) void gemm_proj(
    const int* __restrict__ flag, const void* A0, size_t aoff,
    const void* W, const void* bias, unsigned short* C0, int M, int K, int trans) {
  __shared__ __align__(16) float As[32][64];
  __shared__ __align__(16) float Ws[32][68];
  if (*flag) gemm_proj_body<bf16>(As, Ws, A0, aoff, W, bias, C0, M, K, trans);
  else       gemm_proj_body<float>(As, Ws, A0, aoff, W, bias, C0, M, K, trans);
}

// ---------------------------------------------------------------------------
// In-place RoPE on bf16 (Bc, T, 256) buffer. d=h*64+j pairs with h*64+32+j.
// ---------------------------------------------------------------------------
template<typename T>
__device__ __forceinline__ void rope_body(
    unsigned short* buf, const void* incv, const void* thetav,
    int T_, float inv_seq, int total) {
  const T* inc = (const T*)incv;
  const T* theta = (const T*)thetav;
  int gid = blockIdx.x * 256 + threadIdx.x;
  if (gid >= total) return;
  int j = gid & 31;
  int h = (gid >> 5) & 3;
  int t = (gid >> 7) % T_;
  int b = gid / (T_ * 128);
  float ang = cvt(inc[t]) * inv_seq * cvt(theta[j]);
  float s, c;
  __sincosf(ang, &s, &c);
  size_t base = (size_t)(b * T_ + t) * TD_ + h * 64 + j;
  float x1 = bu2f(buf[base]), x2 = bu2f(buf[base + 32]);
  buf[base]      = f2bu(x1 * c - x2 * s);
  buf[base + 32] = f2bu(x1 * s + x2 * c);
}

__global__ __launch_bounds__(256) void rope_k(
    const int* __restrict__ flag, unsigned short* buf, const void* inc,
    const void* theta, int T_, float inv_seq, int total) {
  if (*flag) rope_body<bf16>(buf, inc, theta, T_, inv_seq, total);
  else       rope_body<float>(buf, inc, theta, T_, inv_seq, total);
}

// ---------------------------------------------------------------------------
// MFMA flash attention. Block = (q-tile 64, h, b), 256 thr = 4 waves, each
// wave owns 16 q rows. Keys processed in 4 tiles of 128. All bf16 MFMA
// (16x16x32): a-frag A[m=lane&15][k=quad*8+j], C/D col=lane&15,row=quad*4+reg.
// Q (t,d) and K (t,d) feed QK^T directly; V^T (d,t) feeds PV directly;
// P round-trips through per-wave LDS to convert C-layout -> a-frag layout.
// ---------------------------------------------------------------------------
__global__ __launch_bounds__(256) void attn_mfma(
    const unsigned short* __restrict__ Q, const unsigned short* __restrict__ K,
    const unsigned short* __restrict__ Vt, const int* __restrict__ tmask,
    unsigned short* __restrict__ AO) {
  const int b = blockIdx.z, h = blockIdx.y, q0 = blockIdx.x * 64;
  __shared__ unsigned short Qs[64][64];
  __shared__ unsigned short Ks[128][64];
  __shared__ unsigned short Vs[64][128];
  __shared__ unsigned short Ps[4][16][128];
  __shared__ float maskf[TTXT];

  const int tid = threadIdx.x;
  const int w = tid >> 6, lane = tid & 63;
  const int lq = lane & 15, quad = lane >> 4;

  // ---- stage Q (zero-padded past 1000) + mask ----
#pragma unroll
  for (int it = 0; it < 2; it++) {
    int c = it * 256 + tid;
    int row = c >> 3, col = (c & 7) * 8;
    int t = q0 + row;
    uint4 v = make_uint4(0u, 0u, 0u, 0u);
    if (t < TLAT)
      v = *(const uint4*)(Q + ((size_t)(b * TLAT + t) * TD_ + h * 64 + col));
    *(uint4*)&Qs[row][col] = v;
  }
  maskf[tid]       = (float)tmask[b * TTXT + tid];
  maskf[tid + 256] = (float)tmask[b * TTXT + 256 + tid];
  __syncthreads();

  short8 qa0 = *(const short8*)&Qs[w * 16 + lq][quad * 8];
  short8 qa1 = *(const short8*)&Qs[w * 16 + lq][32 + quad * 8];

  float m_old[4] = {-1e30f, -1e30f, -1e30f, -1e30f};
  float l[4] = {0.f, 0.f, 0.f, 0.f};
  float4v Oacc[4];
#pragma unroll
  for (int i = 0; i < 4; i++) Oacc[i] = (float4v){0.f, 0.f, 0.f, 0.f};

  for (int kt = 0; kt < 4; kt++) {
    __syncthreads();                       // prior iter done reading Ks/Vs
#pragma unroll
    for (int it = 0; it < 4; it++) {       // K tile: 128 keys x 64 d
      int c = it * 256 + tid;
      int row = c >> 3, col = (c & 7) * 8;
      *(uint4*)&Ks[row][col] =
        *(const uint4*)(K + ((size_t)(b * TTXT + kt * 128 + row) * TD_ + h * 64 + col));
    }
#pragma unroll
    for (int it = 0; it < 4; it++) {       // V^T tile: 64 d x 128 keys
      int c = it * 256 + tid;
      int row = c >> 4, col = (c & 15) * 8;
      *(uint4*)&Vs[row][col] =
        *(const uint4*)(Vt + (((size_t)b * TD_ + h * 64 + row) * TTXT + kt * 128 + col));
    }
    __syncthreads();

    // ---- S = Q K^T for this wave's 16 rows x 128 keys ----
    float4v Sacc[8];
#pragma unroll
    for (int nt = 0; nt < 8; nt++) {
      short8 kb0 = *(const short8*)&Ks[nt * 16 + lq][quad * 8];
      short8 kb1 = *(const short8*)&Ks[nt * 16 + lq][32 + quad * 8];
      float4v s = (float4v){0.f, 0.f, 0.f, 0.f};
      s = __builtin_amdgcn_mfma_f32_16x16x32_bf16(qa0, kb0, s, 0, 0, 0);
      s = __builtin_amdgcn_mfma_f32_16x16x32_bf16(qa1, kb1, s, 0, 0, 0);
      Sacc[nt] = s;
    }
    float mk[8];
#pragma unroll
    for (int nt = 0; nt < 8; nt++) mk[nt] = maskf[kt * 128 + nt * 16 + lq];

    // scale + mask (masked -> -1e30 so it can't raise the max)
#pragma unroll
    for (int nt = 0; nt < 8; nt++)
#pragma unroll
      for (int r = 0; r < 4; r++) {
        float sv = Sacc[nt][r] * SCALE_;
        Sacc[nt][r] = (mk[nt] != 0.f) ? sv : -1e30f;
      }

#pragma unroll
    for (int r = 0; r < 4; r++) {
      float mx = -1e30f;
#pragma unroll
      for (int nt = 0; nt < 8; nt++) mx = fmaxf(mx, Sacc[nt][r]);
      mx = fmaxf(mx, __shfl_xor(mx, 1));
      mx = fmaxf(mx, __shfl_xor(mx, 2));
      mx = fmaxf(mx, __shfl_xor(mx, 4));
      mx = fmaxf(mx, __shfl_xor(mx, 8));
      float mnew = fmaxf(m_old[r], mx);
      float alpha = __expf(m_old[r] - mnew);
      float ps = 0.f;
#pragma unroll
      for (int nt = 0; nt < 8; nt++) {
        float p = (mk[nt] != 0.f) ? __expf(Sacc[nt][r] - mnew) : 0.f;
        ps += p;
        Ps[w][quad * 4 + r][nt * 16 + lq] = f2bu(p);
      }
      ps += __shfl_xor(ps, 1);
      ps += __shfl_xor(ps, 2);
      ps += __shfl_xor(ps, 4);
      ps += __shfl_xor(ps, 8);
      l[r] = alpha * l[r] + ps;
      m_old[r] = mnew;
#pragma unroll
      for (int dt = 0; dt < 4; dt++) Oacc[dt][r] *= alpha;
    }

    // ---- O += P V (P from per-wave LDS; same-wave RAW, no barrier) ----
#pragma unroll
    for (int dt = 0; dt < 4; dt++) {
#pragma unroll
      for (int ks = 0; ks < 4; ks++) {
        short8 pa = *(const short8*)&Ps[w][lq][ks * 32 + quad * 8];
        short8 vb = *(const short8*)&Vs[dt * 16 + lq][ks * 32 + quad * 8];
        Oacc[dt] = __builtin_amdgcn_mfma_f32_16x16x32_bf16(pa, vb, Oacc[dt], 0, 0, 0);
      }
    }
  }

  // ---- normalize + store ----
#pragma unroll
  for (int r = 0; r < 4; r++) {
    int q = q0 + w * 16 + quad * 4 + r;
    if (q < TLAT) {
      float linv = 1.0f / fmaxf(l[r], 1e-30f);
#pragma unroll
      for (int dt = 0; dt < 4; dt++) {
        int d = h * 64 + dt * 16 + lq;
        AO[(size_t)(b * TLAT + q) * TD_ + d] = f2bu(Oacc[dt][r] * linv);
      }
    }
  }
}

// ---------------------------------------------------------------------------
// Output projection + residual + mask:
//   Out[b,c,t] = (x[b,c,t] + sum_d AO[b,t,d]*Wo[c,d] + bo[c]) * lmask[b,t]
// AO is bf16 (ushort bits); X/W/out follow external dtype T.
// ---------------------------------------------------------------------------
template<typename T>
__device__ __forceinline__ void gemm_out_body(
    float (*As)[65], float (*Ws)[65],
    const unsigned short* AO, const void* Wv, const void* biasv,
    const void* Xv, size_t xoff, const void* lmv, size_t lmoff,
    void* Outv, size_t ooff) {
  const T* W    = (const T*)Wv;
  const T* bias = (const T*)biasv;
  const T* X    = (const T*)Xv + xoff;
  const T* lm   = (const T*)lmv + lmoff;
  T* Out        = (T*)Outv + ooff;
  const int b = blockIdx.z;
  const int m0 = blockIdx.x * 64;   // t tile
  const int n0 = blockIdx.y * 64;   // c tile
  const unsigned short* A = AO + (size_t)b * TLAT * TD_;
  float acc[4][4] = {};
  const int tid = threadIdx.x;
  const int tm = (tid & 15) * 4, tn = (tid >> 4) * 4;
  for (int k0 = 0; k0 < TD_; k0 += 32) {
#pragma unroll
    for (int i = 0; i < 8; i++) {
      int idx = i * 256 + tid;
      int mm = idx >> 5, kk = idx & 31;
      int t = m0 + mm;
      As[kk][mm] = (t < TLAT) ? bu2f(A[(size_t)t * TD_ + k0 + kk]) : 0.f;
    }
#pragma unroll
    for (int i = 0; i < 8; i++) {
      int idx = i * 256 + tid;
      int nn = idx >> 5, kk = idx & 31;
      Ws[kk][nn] = cvt(W[(size_t)(n0 + nn) * TD_ + k0 + kk]);
    }
    __syncthreads();
#pragma unroll
    for (int kk = 0; kk < 32; kk++) {
      float a[4], w[4];
#pragma unroll
      for (int i = 0; i < 4; i++) a[i] = As[kk][tm + i];
#pragma unroll
      for (int j = 0; j < 4; j++) w[j] = Ws[kk][tn + j];
#pragma unroll
      for (int i = 0; i < 4; i++)
#pragma unroll
        for (int j = 0; j < 4; j++)
          acc[i][j] = fmaf(a[i], w[j], acc[i][j]);
    }
    __syncthreads();
  }
#pragma unroll
  for (int j = 0; j < 4; j++) {
    int c = n0 + tn + j;
    float bj = cvt(bias[c]);
#pragma unroll
    for (int i = 0; i < 4; i++) {
      int t = m0 + tm + i;
      if (t < TLAT) {
        size_t gi = (size_t)b * CH_ * TLAT + (size_t)c * TLAT + t;
        float val = acc[i][j] + bj + cvt(X[gi]);
        val *= cvt(lm[b * TLAT + t]);
        stv(&Out[gi], val);
      }
    }
  }
}

__global__ __launch_bounds__(256) void gemm_out(
    const int* __restrict__ flag, const unsigned short* AO, const void* W,
    const void* bias, const void* X, size_t xoff,
    const void* lmask, size_t lmoff, void* Out, size_t ooff) {
  __shared__ float As[32][65];
  __shared__ float Ws[32][65];
  if (*flag) gemm_out_body<bf16>(As, Ws, AO, W, bias, X, xoff, lmask, lmoff, Out, ooff);
  else       gemm_out_body<float>(As, Ws, AO, W, bias, X, xoff, lmask, lmoff, Out, ooff);
}

extern "C" void kernel_launch(void* const* d_in, const int* in_sizes, int n_in,
                              void* d_out, int out_size, void* d_ws, size_t ws_size,
                              hipStream_t stream) {
  const void* x        = d_in[0];
  const void* text_emb = d_in[1];
  const void* lmask    = d_in[2];
  const int*  tmask    = (const int*)d_in[3];
  const void* Wq = d_in[4];
  const void* bq = d_in[5];
  const void* Wk = d_in[6];
  const void* bk = d_in[7];
  const void* Wv = d_in[8];
  const void* bv = d_in[9];
  const void* Wo = d_in[10];
  const void* bo = d_in[11];
  const void* theta = d_in[12];
  const void* inc   = d_in[13];

  int* dflag = (int*)d_ws;
  unsigned short* scratch = (unsigned short*)((char*)d_ws + 256);
  size_t avail = (ws_size > 256) ? ws_size - 256 : 0;

  // Per-batch bf16 scratch: q(1000*256) + k(512*256) + vT(256*512) + ao(1000*256)
  const size_t per_b_elems = (size_t)TD_ * (TLAT + TTXT + TTXT + TLAT); // 774144
  const size_t per_b_bytes = per_b_elems * 2;                           // ~1.55 MB
  int Bc = (int)(avail / per_b_bytes);
  if (Bc > B_) Bc = B_;
  if (Bc < 1) Bc = 1;

  unsigned short* qbuf  = scratch;
  unsigned short* kbuf  = qbuf + (size_t)Bc * TLAT * TD_;
  unsigned short* vtbuf = kbuf + (size_t)Bc * TTXT * TD_;
  unsigned short* aobuf = vtbuf + (size_t)Bc * TD_ * TTXT;

  detect_k<<<1, 1, 0, stream>>>(inc, dflag);

  for (int b0 = 0; b0 < B_; b0 += Bc) {
    int bn = B_ - b0; if (bn > Bc) bn = Bc;
    size_t xoff   = (size_t)b0 * CH_ * TLAT;
    size_t emboff = (size_t)b0 * TD_ * TTXT;

    gemm_proj<<<dim3(16, 4, bn), 256, 0, stream>>>(dflag, x,        xoff,   Wq, bq, qbuf,  TLAT, CH_, 0);
    gemm_proj<<<dim3(8,  4, bn), 256, 0, stream>>>(dflag, text_emb, emboff, Wk, bk, kbuf,  TTXT, TD_, 0);
    gemm_proj<<<dim3(8,  4, bn), 256, 0, stream>>>(dflag, text_emb, emboff, Wv, bv, vtbuf, TTXT, TD_, 1);

    int totq = bn * TLAT * 128;
    rope_k<<<(totq + 255) / 256, 256, 0, stream>>>(dflag, qbuf, inc, theta, TLAT, 1.0f / TLAT, totq);
    int totk = bn * TTXT * 128;
    rope_k<<<(totk + 255) / 256, 256, 0, stream>>>(dflag, kbuf, inc, theta, TTXT, 1.0f / TTXT, totk);

    attn_mfma<<<dim3(16, H_, bn), 256, 0, stream>>>(qbuf, kbuf, vtbuf,
                                                    tmask + (size_t)b0 * TTXT, aobuf);

    gemm_out<<<dim3(16, 8, bn), 256, 0, stream>>>(dflag, aobuf, Wo, bo,
                                                  x, xoff, lmask, (size_t)b0 * TLAT,
                                                  d_out, xoff);
  }
}